// Round 1
// baseline (427.123 us; speedup 1.0000x reference)
//
#include <hip/hip_runtime.h>

typedef __bf16 v8bf __attribute__((ext_vector_type(8)));
typedef __bf16 v2bf __attribute__((ext_vector_type(2)));
typedef float  v4f  __attribute__((ext_vector_type(4)));

#define BZv 8
#define NUMv 1024
#define NAv 64
#define FDv 128
#define PTS (BZv*NUMv*NAv)   // 524288

// workspace layout (bytes)
#define OFF_WF1 0        // bf16 [64][128] folded BN
#define OFF_WF2 16384    // bf16 [32][64]
#define OFF_WS2 20480    // bf16 [16][32] (K 8->32 zero pad, folded BN)
#define OFF_WS3 21504    // bf16 [32][32] (K 16->32 zero pad)
#define OFF_WA1 23552    // bf16 [32][64] folded BN
#define OFF_BF1 27648    // f32 [64]
#define OFF_BF2 27904    // f32 [32]
#define OFF_BS2 28032    // f32 [16]
#define OFF_BS3 28096    // f32 [32]
#define OFF_BA1 28224    // f32 [32]
#define OFF_WS1 28352    // f32 [8][4]  (w0,w1,w2,bias) folded BN

#define INVS 0.9999950000374997f   // 1/sqrt(1+1e-5)

__device__ __forceinline__ float tanh_fast(float x) {
    // tanh(x) = 1 - 2/(exp(2x)+1); saturates correctly at +-inf
    float e = __expf(2.0f * x);
    return 1.0f - 2.0f * __builtin_amdgcn_rcpf(e + 1.0f);
}

__global__ void prep_kernel(const float* __restrict__ Wf1, const float* __restrict__ bf1,
                            const float* __restrict__ gf1, const float* __restrict__ btf1,
                            const float* __restrict__ Wf2, const float* __restrict__ bf2,
                            const float* __restrict__ Ws1, const float* __restrict__ bs1,
                            const float* __restrict__ gs1, const float* __restrict__ bts1,
                            const float* __restrict__ Ws2, const float* __restrict__ bs2,
                            const float* __restrict__ gs2, const float* __restrict__ bts2,
                            const float* __restrict__ Ws3, const float* __restrict__ bs3,
                            const float* __restrict__ Wa1, const float* __restrict__ ba1,
                            const float* __restrict__ ga1, const float* __restrict__ bta1,
                            char* __restrict__ ws)
{
    int t = blockIdx.x * blockDim.x + threadIdx.x;
    int stride = gridDim.x * blockDim.x;
    __bf16* wf1b = (__bf16*)(ws + OFF_WF1);
    __bf16* wf2b = (__bf16*)(ws + OFF_WF2);
    __bf16* ws2b = (__bf16*)(ws + OFF_WS2);
    __bf16* ws3b = (__bf16*)(ws + OFF_WS3);
    __bf16* wa1b = (__bf16*)(ws + OFF_WA1);
    float* bf1f = (float*)(ws + OFF_BF1);
    float* bf2f = (float*)(ws + OFF_BF2);
    float* bs2f = (float*)(ws + OFF_BS2);
    float* bs3f = (float*)(ws + OFF_BS3);
    float* ba1f = (float*)(ws + OFF_BA1);
    float* ws1f = (float*)(ws + OFF_WS1);

    for (int i = t; i < 64*128; i += stride) { int o = i >> 7; wf1b[i] = (__bf16)(Wf1[i] * (gf1[o] * INVS)); }
    for (int i = t; i < 32*64;  i += stride) wf2b[i] = (__bf16)Wf2[i];
    for (int i = t; i < 16*32;  i += stride) { int o = i >> 5, k = i & 31;
        ws2b[i] = (k < 8) ? (__bf16)(Ws2[o*8+k] * (gs2[o]*INVS)) : (__bf16)0.0f; }
    for (int i = t; i < 32*32;  i += stride) { int o = i >> 5, k = i & 31;
        ws3b[i] = (k < 16) ? (__bf16)Ws3[o*16+k] : (__bf16)0.0f; }
    for (int i = t; i < 32*64;  i += stride) { int o = i >> 6; wa1b[i] = (__bf16)(Wa1[i] * (ga1[o]*INVS)); }
    for (int i = t; i < 64; i += stride) bf1f[i] = bf1[i]*gf1[i]*INVS + btf1[i];
    for (int i = t; i < 32; i += stride) bf2f[i] = bf2[i];
    for (int i = t; i < 16; i += stride) bs2f[i] = bs2[i]*gs2[i]*INVS + bts2[i];
    for (int i = t; i < 32; i += stride) bs3f[i] = bs3[i];
    for (int i = t; i < 32; i += stride) ba1f[i] = ba1[i]*ga1[i]*INVS + bta1[i];
    for (int i = t; i < 32; i += stride) { int o = i >> 2, k = i & 3;
        ws1f[i] = (k < 3) ? Ws1[o*3+k]*gs1[o]*INVS : (bs1[o]*gs1[o]*INVS + bts1[o]); }
}

// One wave (64 threads) per softmax group: g = b*1024+n, lanes = anchors.
// MFMA 16x16x32 bf16 layouts: A[m=lane&15][k=quad*8+j]; B[k=quad*8+j][n=lane&15];
// C/D: col=lane&15, row=quad*4+reg.
__global__ __launch_bounds__(64, 3) void disarm_main(
    const float* __restrict__ loc, const float* __restrict__ feat,
    const float* __restrict__ wa2, const float* __restrict__ ba2,
    const char* __restrict__ ws, float* __restrict__ out)
{
    __shared__ v8bf hbuf[64 * 8];   // 64 pts x 64 ch (8 chunks of 8 bf16), chunk idx XOR (pt&7)
    __shared__ v8bf sbuf[64 * 4];   // 64 pts x 32 ch (4 chunks), chunk idx XOR (pt&3)

    const int g = blockIdx.x;
    const int lane = threadIdx.x;
    const int l15 = lane & 15;
    const int q = lane >> 4;
    const int b = g >> 10;
    const int n = g & 1023;

    const __bf16* Wf1b = (const __bf16*)(ws + OFF_WF1);
    const __bf16* Wf2b = (const __bf16*)(ws + OFF_WF2);
    const __bf16* Ws2b = (const __bf16*)(ws + OFF_WS2);
    const __bf16* Ws3b = (const __bf16*)(ws + OFF_WS3);
    const __bf16* Wa1b = (const __bf16*)(ws + OFF_WA1);
    const float* bf1f = (const float*)(ws + OFF_BF1);
    const float* bf2f = (const float*)(ws + OFF_BF2);
    const float* bs2f = (const float*)(ws + OFF_BS2);
    const float* bs3f = (const float*)(ws + OFF_BS3);
    const float* ba1f = (const float*)(ws + OFF_BA1);
    const float* ws1f = (const float*)(ws + OFF_WS1);

    const v4f zero4 = {0.0f, 0.0f, 0.0f, 0.0f};

    // ================= stage 1: h = tanh(Wf1'·f + bf1')  (M=64,N=64pts,K=128) ========
    v4f acc[4][4];
    #pragma unroll
    for (int mt = 0; mt < 4; ++mt)
        #pragma unroll
        for (int nt = 0; nt < 4; ++nt) acc[mt][nt] = zero4;

    const float* fb = feat + (size_t)b * (FDv*NUMv*NAv) + (size_t)(q*8) * (NUMv*NAv) + (size_t)n * NAv + l15;
    #pragma unroll
    for (int kt = 0; kt < 4; ++kt) {
        v8bf Af[4];
        #pragma unroll
        for (int mt = 0; mt < 4; ++mt)
            Af[mt] = *(const v8bf*)(Wf1b + (mt*16 + l15) * FDv + kt*32 + q*8);
        v8bf Bf[4];
        #pragma unroll
        for (int nt = 0; nt < 4; ++nt) {
            const float* p = fb + (size_t)(kt*32) * (NUMv*NAv) + nt*16;
            v8bf v;
            #pragma unroll
            for (int j = 0; j < 8; ++j) v[j] = (__bf16)p[(size_t)j * (NUMv*NAv)];
            Bf[nt] = v;
        }
        #pragma unroll
        for (int mt = 0; mt < 4; ++mt)
            #pragma unroll
            for (int nt = 0; nt < 4; ++nt)
                acc[mt][nt] = __builtin_amdgcn_mfma_f32_16x16x32_bf16(Af[mt], Bf[nt], acc[mt][nt], 0, 0, 0);
    }
    #pragma unroll
    for (int mt = 0; mt < 4; ++mt) {
        v4f bia = *(const v4f*)(bf1f + mt*16 + q*4);
        #pragma unroll
        for (int nt = 0; nt < 4; ++nt) {
            int pt = nt*16 + l15;
            #pragma unroll
            for (int rp = 0; rp < 2; ++rp) {
                float t0 = tanh_fast(acc[mt][nt][2*rp+0] + bia[2*rp+0]);
                float t1 = tanh_fast(acc[mt][nt][2*rp+1] + bia[2*rp+1]);
                int cidx = 2*mt + (q >> 1);
                int pairidx = 2*(q & 1) + rp;
                v2bf pr; pr[0] = (__bf16)t0; pr[1] = (__bf16)t1;
                ((v2bf*)&hbuf[pt*8 + (cidx ^ (pt & 7))])[pairidx] = pr;
            }
        }
    }
    __syncthreads();

    // ================= stage 2: feat_dis = Wf2·h + bf2  (M=32,K=64) ========
    v4f facc[2][4];
    #pragma unroll
    for (int mt = 0; mt < 2; ++mt)
        #pragma unroll
        for (int nt = 0; nt < 4; ++nt) facc[mt][nt] = zero4;
    v8bf fA[2][2];
    #pragma unroll
    for (int mt = 0; mt < 2; ++mt)
        #pragma unroll
        for (int kt = 0; kt < 2; ++kt)
            fA[mt][kt] = *(const v8bf*)(Wf2b + (mt*16 + l15)*64 + kt*32 + q*8);
    #pragma unroll
    for (int nt = 0; nt < 4; ++nt) {
        int pt = nt*16 + l15;
        v8bf B0 = hbuf[pt*8 + ((q + 0) ^ (pt & 7))];
        v8bf B1 = hbuf[pt*8 + ((q + 4) ^ (pt & 7))];
        #pragma unroll
        for (int mt = 0; mt < 2; ++mt) {
            facc[mt][nt] = __builtin_amdgcn_mfma_f32_16x16x32_bf16(fA[mt][0], B0, facc[mt][nt], 0, 0, 0);
            facc[mt][nt] = __builtin_amdgcn_mfma_f32_16x16x32_bf16(fA[mt][1], B1, facc[mt][nt], 0, 0, 0);
        }
    }
    __syncthreads();   // all h reads done before overwriting hbuf
    #pragma unroll
    for (int mt = 0; mt < 2; ++mt) {
        v4f bia = *(const v4f*)(bf2f + mt*16 + q*4);
        #pragma unroll
        for (int nt = 0; nt < 4; ++nt) {
            int pt = nt*16 + l15;
            #pragma unroll
            for (int rp = 0; rp < 2; ++rp) {
                float t0 = facc[mt][nt][2*rp+0] + bia[2*rp+0];
                float t1 = facc[mt][nt][2*rp+1] + bia[2*rp+1];
                int cidx = 4 + 2*mt + (q >> 1);      // cat channels 32..63
                int pairidx = 2*(q & 1) + rp;
                v2bf pr; pr[0] = (__bf16)t0; pr[1] = (__bf16)t1;
                ((v2bf*)&hbuf[pt*8 + (cidx ^ (pt & 7))])[pairidx] = pr;
            }
        }
    }

    // ================= stage 3: spatial branch ========
    {   // zero own row of sbuf (padding for K=32 MFMA reads)
        v8bf z8; 
        #pragma unroll
        for (int j = 0; j < 8; ++j) z8[j] = (__bf16)0.0f;
        #pragma unroll
        for (int c = 0; c < 4; ++c) sbuf[lane*4 + c] = z8;
    }
    // s1 = tanh(Ws1'·loc + b) per-lane VALU (weights wave-uniform -> scalar loads)
    const float* lp = loc + ((size_t)g * 64 + lane) * 3;
    float x0 = lp[0], x1 = lp[1], x2 = lp[2];
    float s1v[8];
    #pragma unroll
    for (int o = 0; o < 8; ++o) {
        float w0 = ws1f[o*4+0], w1 = ws1f[o*4+1], w2 = ws1f[o*4+2], bb = ws1f[o*4+3];
        s1v[o] = tanh_fast(w0*x0 + w1*x1 + w2*x2 + bb);
    }
    {
        v2bf* dst = (v2bf*)&sbuf[lane*4 + (0 ^ (lane & 3))];
        #pragma unroll
        for (int pp = 0; pp < 4; ++pp) {
            v2bf pr; pr[0] = (__bf16)s1v[2*pp]; pr[1] = (__bf16)s1v[2*pp+1];
            dst[pp] = pr;
        }
    }
    __syncthreads();
    // s2 = tanh(Ws2'·s1 + bs2')  (M=16, K=32 padded)
    v8bf sA = *(const v8bf*)(Ws2b + l15*32 + q*8);
    v4f sacc[4];
    #pragma unroll
    for (int nt = 0; nt < 4; ++nt) sacc[nt] = zero4;
    #pragma unroll
    for (int nt = 0; nt < 4; ++nt) {
        int pt = nt*16 + l15;
        sacc[nt] = __builtin_amdgcn_mfma_f32_16x16x32_bf16(sA, sbuf[pt*4 + (q ^ (pt & 3))], sacc[nt], 0, 0, 0);
    }
    __syncthreads();   // s1 reads done before overwrite
    {
        v4f bia = *(const v4f*)(bs2f + q*4);
        #pragma unroll
        for (int nt = 0; nt < 4; ++nt) {
            int pt = nt*16 + l15;
            #pragma unroll
            for (int rp = 0; rp < 2; ++rp) {
                float t0 = tanh_fast(sacc[nt][2*rp+0] + bia[2*rp+0]);
                float t1 = tanh_fast(sacc[nt][2*rp+1] + bia[2*rp+1]);
                int cidx = (q >> 1);                 // ch 0..15
                int pairidx = 2*(q & 1) + rp;
                v2bf pr; pr[0] = (__bf16)t0; pr[1] = (__bf16)t1;
                ((v2bf*)&sbuf[pt*4 + (cidx ^ (pt & 3))])[pairidx] = pr;
            }
        }
    }
    __syncthreads();
    // spa_dis = Ws3'·s2 + bs3  (M=32, K=32 padded, no tanh) -> hbuf chunks 0..3
    v8bf a3[2];
    a3[0] = *(const v8bf*)(Ws3b + l15*32 + q*8);
    a3[1] = *(const v8bf*)(Ws3b + (16 + l15)*32 + q*8);
    v4f pacc[2][4];
    #pragma unroll
    for (int mt = 0; mt < 2; ++mt)
        #pragma unroll
        for (int nt = 0; nt < 4; ++nt) pacc[mt][nt] = zero4;
    #pragma unroll
    for (int nt = 0; nt < 4; ++nt) {
        int pt = nt*16 + l15;
        v8bf Bv = sbuf[pt*4 + (q ^ (pt & 3))];
        pacc[0][nt] = __builtin_amdgcn_mfma_f32_16x16x32_bf16(a3[0], Bv, pacc[0][nt], 0, 0, 0);
        pacc[1][nt] = __builtin_amdgcn_mfma_f32_16x16x32_bf16(a3[1], Bv, pacc[1][nt], 0, 0, 0);
    }
    #pragma unroll
    for (int mt = 0; mt < 2; ++mt) {
        v4f bia = *(const v4f*)(bs3f + mt*16 + q*4);
        #pragma unroll
        for (int nt = 0; nt < 4; ++nt) {
            int pt = nt*16 + l15;
            #pragma unroll
            for (int rp = 0; rp < 2; ++rp) {
                float t0 = pacc[mt][nt][2*rp+0] + bia[2*rp+0];
                float t1 = pacc[mt][nt][2*rp+1] + bia[2*rp+1];
                int cidx = 2*mt + (q >> 1);          // cat channels 0..31
                int pairidx = 2*(q & 1) + rp;
                v2bf pr; pr[0] = (__bf16)t0; pr[1] = (__bf16)t1;
                ((v2bf*)&hbuf[pt*8 + (cidx ^ (pt & 7))])[pairidx] = pr;
            }
        }
    }
    __syncthreads();

    // ================= stage 4: a = tanh(Wa1'·cat + ba1')  (M=32,K=64) ========
    v8bf gA[2][2];
    #pragma unroll
    for (int mt = 0; mt < 2; ++mt)
        #pragma unroll
        for (int kt = 0; kt < 2; ++kt)
            gA[mt][kt] = *(const v8bf*)(Wa1b + (mt*16 + l15)*64 + kt*32 + q*8);
    v4f gacc[2][4];
    #pragma unroll
    for (int mt = 0; mt < 2; ++mt)
        #pragma unroll
        for (int nt = 0; nt < 4; ++nt) gacc[mt][nt] = zero4;
    #pragma unroll
    for (int nt = 0; nt < 4; ++nt) {
        int pt = nt*16 + l15;
        v8bf B0 = hbuf[pt*8 + ((q + 0) ^ (pt & 7))];
        v8bf B1 = hbuf[pt*8 + ((q + 4) ^ (pt & 7))];
        #pragma unroll
        for (int mt = 0; mt < 2; ++mt) {
            gacc[mt][nt] = __builtin_amdgcn_mfma_f32_16x16x32_bf16(gA[mt][0], B0, gacc[mt][nt], 0, 0, 0);
            gacc[mt][nt] = __builtin_amdgcn_mfma_f32_16x16x32_bf16(gA[mt][1], B1, gacc[mt][nt], 0, 0, 0);
        }
    }
    __syncthreads();
    #pragma unroll
    for (int mt = 0; mt < 2; ++mt) {
        v4f bia = *(const v4f*)(ba1f + mt*16 + q*4);
        #pragma unroll
        for (int nt = 0; nt < 4; ++nt) {
            int pt = nt*16 + l15;
            #pragma unroll
            for (int rp = 0; rp < 2; ++rp) {
                float t0 = tanh_fast(gacc[mt][nt][2*rp+0] + bia[2*rp+0]);
                float t1 = tanh_fast(gacc[mt][nt][2*rp+1] + bia[2*rp+1]);
                int cidx = 2*mt + (q >> 1);
                int pairidx = 2*(q & 1) + rp;
                v2bf pr; pr[0] = (__bf16)t0; pr[1] = (__bf16)t1;
                ((v2bf*)&sbuf[pt*4 + (cidx ^ (pt & 3))])[pairidx] = pr;
            }
        }
    }
    __syncthreads();

    // ================= stage 5: out = Wa2·a + ba2; tanh; softmax; min-max ========
    float av[32];
    #pragma unroll
    for (int c = 0; c < 4; ++c) {
        v8bf ch = sbuf[lane*4 + (c ^ (lane & 3))];
        #pragma unroll
        for (int j = 0; j < 8; ++j) av[c*8 + j] = (float)ch[j];
    }
    float outv = ba2[0];
    #pragma unroll
    for (int k = 0; k < 32; ++k) outv += av[k] * wa2[k];   // wa2 wave-uniform -> scalar loads
    float t = tanh_fast(outv);

    float mx = t;
    #pragma unroll
    for (int d = 1; d < 64; d <<= 1) mx = fmaxf(mx, __shfl_xor(mx, d));
    float e = __expf(t - mx);
    float sm = e;
    #pragma unroll
    for (int d = 1; d < 64; d <<= 1) sm += __shfl_xor(sm, d);
    float w = e / sm;
    float wmn = w, wmx = w;
    #pragma unroll
    for (int d = 1; d < 64; d <<= 1) {
        wmn = fminf(wmn, __shfl_xor(wmn, d));
        wmx = fmaxf(wmx, __shfl_xor(wmx, d));
    }
    float kk = (1.0f + 1e-6f) / (wmx - wmn + 1e-6f);
    float wn = kk * (w - wmn);

    size_t po = (size_t)g * 64 + lane;
    out[po] = w;
    out[(size_t)PTS + po] = wn;
}

extern "C" void kernel_launch(void* const* d_in, const int* in_sizes, int n_in,
                              void* d_out, int out_size, void* d_ws, size_t ws_size,
                              hipStream_t stream) {
    const float* loc  = (const float*)d_in[0];
    const float* feat = (const float*)d_in[1];
    prep_kernel<<<32, 256, 0, stream>>>(
        (const float*)d_in[2],  (const float*)d_in[3],  (const float*)d_in[4],  (const float*)d_in[5],
        (const float*)d_in[6],  (const float*)d_in[7],
        (const float*)d_in[8],  (const float*)d_in[9],  (const float*)d_in[10], (const float*)d_in[11],
        (const float*)d_in[12], (const float*)d_in[13], (const float*)d_in[14], (const float*)d_in[15],
        (const float*)d_in[16], (const float*)d_in[17],
        (const float*)d_in[18], (const float*)d_in[19], (const float*)d_in[20], (const float*)d_in[21],
        (char*)d_ws);
    disarm_main<<<BZv*NUMv, 64, 0, stream>>>(
        loc, feat, (const float*)d_in[22], (const float*)d_in[23],
        (const char*)d_ws, (float*)d_out);
}